// Round 1
// baseline (1677.766 us; speedup 1.0000x reference)
//
#include <hip/hip_runtime.h>
#include <math.h>

#define H    2048
#define FFN  8192
#define NH   8
#define HD   256
#define SEQ  4096
#define NC   2048
#define TKC  32
#define VPC  64
#define EPS  1e-6f

// ---------- reduction helpers (256-thread blocks = 4 waves) ----------
__device__ inline float wave_sum(float v) {
#pragma unroll
    for (int o = 32; o; o >>= 1) v += __shfl_xor(v, o, 64);
    return v;
}
__device__ inline float block_sum(float v, float* sh) {
    v = wave_sum(v);
    __syncthreads();
    if ((threadIdx.x & 63) == 0) sh[threadIdx.x >> 6] = v;
    __syncthreads();
    return sh[0] + sh[1] + sh[2] + sh[3];
}
__device__ inline float block_max(float v, float* sh) {
#pragma unroll
    for (int o = 32; o; o >>= 1) v = fmaxf(v, __shfl_xor(v, o, 64));
    __syncthreads();
    if ((threadIdx.x & 63) == 0) sh[threadIdx.x >> 6] = v;
    __syncthreads();
    return fmaxf(fmaxf(sh[0], sh[1]), fmaxf(sh[2], sh[3]));
}
__device__ inline float gelu_t(float x) {
    float x3 = x * x * x;
    return 0.5f * x * (1.f + tanhf(0.7978845608028654f * (x + 0.044715f * x3)));
}

// ---------- GEMV: wave per row, float4 coalesced ----------
template <int K>
__global__ __launch_bounds__(256) void gemv_k(const float* __restrict__ W,
                                              const float* __restrict__ x,
                                              float* __restrict__ y) {
    int row = blockIdx.x * 4 + (threadIdx.x >> 6);
    int lane = threadIdx.x & 63;
    const float4* Wr = (const float4*)(W + (size_t)row * K);
    const float4* xv = (const float4*)x;
    float acc = 0.f;
#pragma unroll
    for (int i = 0; i < K / 256; i++) {
        float4 w = Wr[lane + i * 64];
        float4 b = xv[lane + i * 64];
        acc += w.x * b.x + w.y * b.y + w.z * b.z + w.w * b.w;
    }
    acc = wave_sum(acc);
    if (lane == 0) y[row] = acc;
}

// x = W1 @ e + W2 @ p   (input combine, K = 2048)
__global__ __launch_bounds__(256) void gemv2_k(const float* __restrict__ W1,
                                               const float* __restrict__ x1,
                                               const float* __restrict__ W2,
                                               const float* __restrict__ x2,
                                               float* __restrict__ y) {
    int row = blockIdx.x * 4 + (threadIdx.x >> 6);
    int lane = threadIdx.x & 63;
    const float4* W1r = (const float4*)(W1 + (size_t)row * H);
    const float4* W2r = (const float4*)(W2 + (size_t)row * H);
    const float4* x1v = (const float4*)x1;
    const float4* x2v = (const float4*)x2;
    float acc = 0.f;
#pragma unroll
    for (int i = 0; i < H / 256; i++) {
        float4 w = W1r[lane + i * 64], b = x1v[lane + i * 64];
        acc += w.x * b.x + w.y * b.y + w.z * b.z + w.w * b.w;
        w = W2r[lane + i * 64]; b = x2v[lane + i * 64];
        acc += w.x * b.x + w.y * b.y + w.z * b.z + w.w * b.w;
    }
    acc = wave_sum(acc);
    if (lane == 0) y[row] = acc;
}

// act = gelu(Wg@h) * (Wu@h)  — wave per row, K=2048
__global__ __launch_bounds__(256) void gateup_k(const float* __restrict__ Wg,
                                                const float* __restrict__ Wu,
                                                const float* __restrict__ h,
                                                float* __restrict__ act) {
    int row = blockIdx.x * 4 + (threadIdx.x >> 6);
    int lane = threadIdx.x & 63;
    const float4* Wgr = (const float4*)(Wg + (size_t)row * H);
    const float4* Wur = (const float4*)(Wu + (size_t)row * H);
    const float4* hv = (const float4*)h;
    float ag = 0.f, au = 0.f;
#pragma unroll
    for (int i = 0; i < H / 256; i++) {
        float4 b = hv[lane + i * 64];
        float4 w = Wgr[lane + i * 64];
        ag += w.x * b.x + w.y * b.y + w.z * b.z + w.w * b.w;
        w = Wur[lane + i * 64];
        au += w.x * b.x + w.y * b.y + w.z * b.z + w.w * b.w;
    }
    ag = wave_sum(ag);
    au = wave_sum(au);
    if (lane == 0) act[row] = gelu_t(ag) * au;
}

// ---------- single-block norm kernels (256 thr, 8 elem/thr, H=2048) ----------
__global__ __launch_bounds__(256) void rmsnorm_k(const float* __restrict__ x,
                                                 const float* __restrict__ w,
                                                 float* __restrict__ out) {
    __shared__ float sh[4];
    float v[8];
    float ss = 0.f;
#pragma unroll
    for (int j = 0; j < 8; j++) {
        int i = threadIdx.x + j * 256;
        v[j] = x[i];
        ss += v[j] * v[j];
    }
    ss = block_sum(ss, sh);
    float sc = rsqrtf(ss / (float)H + EPS);
#pragma unroll
    for (int j = 0; j < 8; j++) {
        int i = threadIdx.x + j * 256;
        out[i] = v[j] * sc * w[i];
    }
}

// x += rmsnorm(t, w1);  h_out = rmsnorm(x_new, w2)
__global__ __launch_bounds__(256) void addnorm_norm_k(const float* __restrict__ t,
                                                      const float* __restrict__ w1,
                                                      float* __restrict__ x,
                                                      const float* __restrict__ w2,
                                                      float* __restrict__ h_out) {
    __shared__ float sh[4];
    float tv[8], xv[8];
    float ss = 0.f;
#pragma unroll
    for (int j = 0; j < 8; j++) {
        int i = threadIdx.x + j * 256;
        tv[j] = t[i];
        ss += tv[j] * tv[j];
    }
    ss = block_sum(ss, sh);
    float sc = rsqrtf(ss / (float)H + EPS);
    float ss2 = 0.f;
#pragma unroll
    for (int j = 0; j < 8; j++) {
        int i = threadIdx.x + j * 256;
        xv[j] = x[i] + tv[j] * sc * w1[i];
        x[i] = xv[j];
        ss2 += xv[j] * xv[j];
    }
    ss2 = block_sum(ss2, sh);
    float sc2 = rsqrtf(ss2 / (float)H + EPS);
#pragma unroll
    for (int j = 0; j < 8; j++) {
        int i = threadIdx.x + j * 256;
        h_out[i] = xv[j] * sc2 * w2[i];
    }
}

// per-head q rmsnorm + RoPE; 8 blocks x 256 threads
__global__ __launch_bounds__(256) void qnorm_rope_k(float* __restrict__ q,
                                                    const float* __restrict__ qn,
                                                    const float* __restrict__ cosv,
                                                    const float* __restrict__ sinv) {
    __shared__ float sh[4];
    __shared__ float qs[HD];
    int hh = blockIdx.x, d = threadIdx.x;
    float v = q[hh * HD + d];
    float ss = block_sum(v * v, sh);
    float sc = rsqrtf(ss / (float)HD + EPS);
    qs[d] = v * sc * qn[d];
    __syncthreads();
    float c, s, rot;
    if (d < HD / 2) { c = cosv[d]; s = sinv[d]; rot = -qs[d + HD / 2]; }
    else           { c = cosv[d - HD / 2]; s = sinv[d - HD / 2]; rot = qs[d - HD / 2]; }
    q[hh * HD + d] = qs[d] * c + rot * s;
}

// scores[n,s] = q[n]·K[n,s] + mask[s] — wave per (n,s); grid = NH*SEQ/4
__global__ __launch_bounds__(256) void scores_k(const float* __restrict__ kv_k,
                                                const float* __restrict__ q,
                                                const float* __restrict__ mask,
                                                float* __restrict__ sc) {
    int r = blockIdx.x * 4 + (threadIdx.x >> 6);
    int lane = threadIdx.x & 63;
    int n = r >> 12, s = r & (SEQ - 1);
    const float4* kr = (const float4*)(kv_k + ((size_t)n * SEQ + s) * HD);
    const float4* qv = (const float4*)(q + n * HD);
    float4 k4 = kr[lane], q4 = qv[lane];
    float acc = k4.x * q4.x + k4.y * q4.y + k4.z * q4.z + k4.w * q4.w;
    acc = wave_sum(acc);
    if (lane == 0) sc[r] = acc + mask[s];
}

// softmax per head over SEQ; 8 blocks x 256 threads, 16 elem/thr
__global__ __launch_bounds__(256) void softmax_k(float* __restrict__ sc) {
    __shared__ float sh[4];
    float* p = sc + blockIdx.x * SEQ;
    float v[16];
    float lm = -1e30f;
#pragma unroll
    for (int j = 0; j < 16; j++) {
        v[j] = p[threadIdx.x + j * 256];
        lm = fmaxf(lm, v[j]);
    }
    float m = block_max(lm, sh);
    float ls = 0.f;
#pragma unroll
    for (int j = 0; j < 16; j++) {
        v[j] = expf(v[j] - m);
        ls += v[j];
    }
    float ssum = block_sum(ls, sh);
    float inv = 1.f / ssum;
#pragma unroll
    for (int j = 0; j < 16; j++) p[threadIdx.x + j * 256] = v[j] * inv;
}

// o[n,d] = sum_s attn[n,s]*V[n,d,s] — wave per (n,d); grid = NH*HD/4
__global__ __launch_bounds__(256) void av_k(const float* __restrict__ kv_v,
                                            const float* __restrict__ attn,
                                            float* __restrict__ o) {
    int r = blockIdx.x * 4 + (threadIdx.x >> 6);
    int lane = threadIdx.x & 63;
    int n = r >> 8, d = r & (HD - 1);
    const float4* vr = (const float4*)(kv_v + ((size_t)n * HD + d) * SEQ);
    const float4* ar = (const float4*)(attn + (size_t)n * SEQ);
    float acc = 0.f;
#pragma unroll
    for (int i = 0; i < SEQ / 256; i++) {
        float4 vv = vr[lane + i * 64], aa = ar[lane + i * 64];
        acc += vv.x * aa.x + vv.y * aa.y + vv.z * aa.z + vv.w * aa.w;
    }
    acc = wave_sum(acc);
    if (lane == 0) o[r] = acc;
}

// top-32 clusters of c_logits + build sel[2048]; one block
__global__ __launch_bounds__(256) void top32_sel_k(const float* __restrict__ cl,
                                                   const int* __restrict__ tord,
                                                   int* __restrict__ sel) {
    __shared__ float sv[NC];
    __shared__ float rv[256];
    __shared__ int ri[256];
    __shared__ int topc[TKC];
    int tid = threadIdx.x;
#pragma unroll
    for (int j = 0; j < NC / 256; j++) sv[tid + j * 256] = cl[tid + j * 256];
    __syncthreads();
    for (int t = 0; t < TKC; t++) {
        float bv = -1e30f;
        int bi = 0;
#pragma unroll
        for (int j = 0; j < NC / 256; j++) {
            int i = tid * (NC / 256) + j;
            float v = sv[i];
            if (v > bv) { bv = v; bi = i; }
        }
        rv[tid] = bv; ri[tid] = bi;
        __syncthreads();
        for (int s = 128; s; s >>= 1) {
            if (tid < s) {
                if (rv[tid + s] > rv[tid] ||
                    (rv[tid + s] == rv[tid] && ri[tid + s] < ri[tid])) {
                    rv[tid] = rv[tid + s]; ri[tid] = ri[tid + s];
                }
            }
            __syncthreads();
        }
        if (tid == 0) { topc[t] = ri[0]; sv[ri[0]] = -1e30f; }
        __syncthreads();
    }
    // sel[i] = token_ordering[topc[i/VPC]*VPC + i%VPC]
    for (int i = tid; i < TKC * VPC; i += 256)
        sel[i] = tord[topc[i >> 6] * VPC + (i & (VPC - 1))];
}

// logits over gathered vocab rows — wave per row; grid = 2048/4
__global__ __launch_bounds__(256) void sel_dot_k(const float* __restrict__ lm,
                                                 const int* __restrict__ sel,
                                                 const float* __restrict__ hv,
                                                 float* __restrict__ out) {
    int r = blockIdx.x * 4 + (threadIdx.x >> 6);
    int lane = threadIdx.x & 63;
    const float4* Wr = (const float4*)(lm + (size_t)sel[r] * H);
    const float4* xv = (const float4*)hv;
    float acc = 0.f;
#pragma unroll
    for (int i = 0; i < H / 256; i++) {
        float4 w = Wr[lane + i * 64], b = xv[lane + i * 64];
        acc += w.x * b.x + w.y * b.y + w.z * b.z + w.w * b.w;
    }
    acc = wave_sum(acc);
    if (lane == 0) out[r] = acc;
}

// top-8 of sel_logits → out[0..7]=ids (as float), out[8..15]=vals; one block
__global__ __launch_bounds__(256) void top8_k(const float* __restrict__ sl,
                                              const int* __restrict__ sel,
                                              float* __restrict__ out) {
    __shared__ float sv[TKC * VPC];
    __shared__ float rv[256];
    __shared__ int ri[256];
    int tid = threadIdx.x;
#pragma unroll
    for (int j = 0; j < (TKC * VPC) / 256; j++) sv[tid + j * 256] = sl[tid + j * 256];
    __syncthreads();
    for (int t = 0; t < 8; t++) {
        float bv = -1e30f;
        int bi = 0;
#pragma unroll
        for (int j = 0; j < 8; j++) {
            int i = tid * 8 + j;
            float v = sv[i];
            if (v > bv) { bv = v; bi = i; }
        }
        rv[tid] = bv; ri[tid] = bi;
        __syncthreads();
        for (int s = 128; s; s >>= 1) {
            if (tid < s) {
                if (rv[tid + s] > rv[tid] ||
                    (rv[tid + s] == rv[tid] && ri[tid + s] < ri[tid])) {
                    rv[tid] = rv[tid + s]; ri[tid] = ri[tid + s];
                }
            }
            __syncthreads();
        }
        if (tid == 0) {
            out[t] = (float)sel[ri[0]];
            out[8 + t] = rv[0];
            sv[ri[0]] = -1e30f;
        }
        __syncthreads();
    }
}

extern "C" void kernel_launch(void* const* d_in, const int* in_sizes, int n_in,
                              void* d_out, int out_size, void* d_ws, size_t ws_size,
                              hipStream_t stream) {
    const float* embed  = (const float*)d_in[0];
    const float* proj   = (const float*)d_in[1];
    const float* kv_k_[2] = { (const float*)d_in[2], (const float*)d_in[4] };
    const float* kv_v_[2] = { (const float*)d_in[3], (const float*)d_in[5] };
    const float* cos_[2]  = { (const float*)d_in[6], (const float*)d_in[8] };
    const float* sin_[2]  = { (const float*)d_in[7], (const float*)d_in[9] };
    const float* mask_[2] = { (const float*)d_in[10], (const float*)d_in[11] };
    const float* w_in_e = (const float*)d_in[12];
    const float* w_in_p = (const float*)d_in[13];
    const float* final_norm_w = (const float*)d_in[14];
    const float* w_post_proj  = (const float*)d_in[15];
    const float* lm_head      = (const float*)d_in[16];
    const float* centroids    = (const float*)d_in[17];
    const int*   token_order  = (const int*)d_in[18];

    // layer param base: 19 + 10*l : ln_in, ln_pa, ln_pf, ln_pof, qn, wq, wo, wg, wu, wd
    const float* P[2][10];
    for (int l = 0; l < 2; l++)
        for (int j = 0; j < 10; j++) P[l][j] = (const float*)d_in[19 + 10 * l + j];

    float* wsf  = (float*)d_ws;
    float* x    = wsf;                // 2048
    float* h    = wsf + 2048;         // 2048
    float* q    = wsf + 4096;         // 2048
    float* o    = wsf + 6144;         // 2048
    float* tmp  = wsf + 8192;         // 2048
    float* act  = wsf + 10240;        // 8192
    float* attn = wsf + 18432;        // 32768
    float* cl   = wsf + 51200;        // 2048
    float* slog = wsf + 53248;        // 2048
    int*   sel  = (int*)(wsf + 55296);// 2048

    float* out = (float*)d_out;

    // x = w_in_e@embed + w_in_p@proj
    gemv2_k<<<512, 256, 0, stream>>>(w_in_e, embed, w_in_p, proj, x);
    // h = rmsnorm(x, l0_ln_in)
    rmsnorm_k<<<1, 256, 0, stream>>>(x, P[0][0], h);

    for (int l = 0; l < 2; l++) {
        const float* ln_pa = P[l][1];
        const float* ln_pf = P[l][2];
        const float* ln_pof = P[l][3];
        const float* qn = P[l][4];
        const float* wq = P[l][5];
        const float* wo = P[l][6];
        const float* wg = P[l][7];
        const float* wu = P[l][8];
        const float* wd = P[l][9];

        gemv_k<2048><<<512, 256, 0, stream>>>(wq, h, q);
        qnorm_rope_k<<<8, 256, 0, stream>>>(q, qn, cos_[l], sin_[l]);
        scores_k<<<NH * SEQ / 4, 256, 0, stream>>>(kv_k_[l], q, mask_[l], attn);
        softmax_k<<<NH, 256, 0, stream>>>(attn);
        av_k<<<NH * HD / 4, 256, 0, stream>>>(kv_v_[l], attn, o);
        gemv_k<2048><<<512, 256, 0, stream>>>(wo, o, tmp);
        // x += rmsnorm(tmp, ln_pa); h = rmsnorm(x, ln_pf)
        addnorm_norm_k<<<1, 256, 0, stream>>>(tmp, ln_pa, x, ln_pf, h);
        gateup_k<<<FFN / 4, 256, 0, stream>>>(wg, wu, h, act);
        gemv_k<8192><<<512, 256, 0, stream>>>(wd, act, tmp);
        // x += rmsnorm(tmp, ln_pof); h = rmsnorm(x, next_norm)
        const float* next_w = (l == 0) ? P[1][0] : final_norm_w;
        addnorm_norm_k<<<1, 256, 0, stream>>>(tmp, ln_pof, x, next_w, h);
    }

    // h == hv (final-normed hidden)
    gemv_k<2048><<<512, 256, 0, stream>>>(centroids, h, cl);
    top32_sel_k<<<1, 256, 0, stream>>>(cl, token_order, sel);
    sel_dot_k<<<512, 256, 0, stream>>>(lm_head, sel, h, slog);
    top8_k<<<1, 256, 0, stream>>>(slog, sel, out);
    gemv_k<2048><<<512, 256, 0, stream>>>(w_post_proj, h, out + 16);
}